// Round 7
// baseline (133.781 us; speedup 1.0000x reference)
//
#include <hip/hip_runtime.h>

namespace {

constexpr int Bn    = 10;
constexpr int H     = 320;
constexpr int W     = 1024;
constexpr int PTS   = 500;
constexpr int DENSE = 2000;
constexpr int N     = Bn * PTS;   // 5000 rows
constexpr int HWp   = H * W;
constexpr int KITER = 10;
constexpr int RPB   = 4;          // phase B: one row per wave, 4 waves/block

// disp window: rows cy-7..cy+7, cols cx-11..cx+12 (padded to 24)
constexpr int WY   = 15;
constexpr int WX   = 24;
constexpr int WSZ  = WY * WX;       // 360 words = 1440 B per wave
constexpr int WOFF = 7 * WX + 11;   // center offset inside the window

// ---- Phase A: thread-per-row validity. 5000 threads = 79 waves total.
// Each thread: cx/cy (coalesced) -> 25 forepred loads (independent, 25-deep
// MLP) -> 9 sobel taps + maxpool in registers -> flag + zero-store invalid.
__global__ __launch_bounds__(256)
void validity_kernel(const float* __restrict__ disp,
                     const float* __restrict__ forepred,
                     const int*   __restrict__ centerx,
                     const int*   __restrict__ centery,
                     int*         __restrict__ flags,
                     float*       __restrict__ out)
{
    const int row = blockIdx.x * 256 + threadIdx.x;
    if (row >= N) return;
    const int b  = row / PTS;
    const int cx = centerx[row];
    const int cy = centery[row];
    const float* fb = forepred + b * HWp;

    // 5x5 forepred patch (centers >=11 from all borders: SAME padding and
    // the 4-pixel border zeroing of the reference are unreachable here).
    float F[5][5];
    #pragma unroll
    for (int a = 0; a < 5; ++a)
        #pragma unroll
        for (int c = 0; c < 5; ++c)
            F[a][c] = fb[(cy - 2 + a) * W + (cx - 2 + c)];

    float v = 0.f;
    #pragma unroll
    for (int dy = 0; dy < 3; ++dy)
        #pragma unroll
        for (int dx = 0; dx < 3; ++dx) {
            const float g = (F[dy    ][dx + 2] - F[dy    ][dx])
                    + 2.f * (F[dy + 1][dx + 2] - F[dy + 1][dx])
                    +       (F[dy + 2][dx + 2] - F[dy + 2][dx]);
            v = fmaxf(v, fabsf(g));
        }
    const float dcen = disp[b * HWp + cy * W + cx];
    const float mgv  = fmaxf(v * ((dcen > 0.007f) ? 1.f : 0.f), 3.f) - 3.f;
    const bool valid = mgv > 0.1f;

    flags[row] = valid ? 1 : 0;
    if (!valid) {
        // Reference: out = km * keep with keep=0; km is provably finite here
        // (Large cluster always retains the max sample) -> exact zeros.
        out[row * 2 + 0] = 0.f;
        out[row * 2 + 1] = 0.f;
    }
}

// ---- Phase B: wave-per-row for valid rows only (round-6 proven path).
// No barriers: per-wave LDS slice; same-wave ds_write->ds_read is in-order.
__global__ __launch_bounds__(256, 4)
void kmeans_kernel(const float* __restrict__ disp,
                   const int*   __restrict__ centerx,
                   const int*   __restrict__ centery,
                   const int*   __restrict__ bx,
                   const int*   __restrict__ by,
                   const int*   __restrict__ flags,
                   float*       __restrict__ out)
{
    __shared__ float win[RPB][WSZ];

    const int wid  = threadIdx.x >> 6;
    const int lane = threadIdx.x & 63;
    const int row  = blockIdx.x * RPB + wid;   // 0..4999

    if (flags[row] == 0) return;               // wave-uniform; out already 0

    const int b  = row / PTS;
    const int cx = centerx[row];
    const int cy = centery[row];
    const float* db = disp + b * HWp;

    // stage the 15x24 disp window into this wave's LDS slice
    float* wl = win[wid];
    const int gbase = (cy - 7) * W + (cx - 11);
    #pragma unroll
    for (int i = 0; i < 6; ++i) {
        const int w = lane + 64 * i;
        if (w < WSZ) {
            const unsigned r = (unsigned)w / 24u;
            const unsigned c = (unsigned)w - r * 24u;
            wl[w] = db[gbase + r * W + c];
        }
    }

    // gather 2000 samples (32/lane); bx/by as int4 (coalesced 16B/lane)
    const int4* bx4 = reinterpret_cast<const int4*>(bx + row * DENSE);
    const int4* by4 = reinterpret_cast<const int4*>(by + row * DENSE);

    float s[32];
    float mx = -INFINITY, mn = INFINITY, tot = 0.f;
    #pragma unroll
    for (int k = 0; k < 8; ++k) {
        const int q = lane + 64 * k;        // int4 index, 500 total
        if (q < DENSE / 4) {                 // only k==7 partially masked
            const int4 xb = bx4[q];
            const int4 yb = by4[q];
            const float x0 = wl[yb.x * WX + xb.x + WOFF];
            const float x1 = wl[yb.y * WX + xb.y + WOFF];
            const float x2 = wl[yb.z * WX + xb.z + WOFF];
            const float x3 = wl[yb.w * WX + xb.w + WOFF];
            s[k * 4 + 0] = x0; s[k * 4 + 1] = x1;
            s[k * 4 + 2] = x2; s[k * 4 + 3] = x3;
            mx = fmaxf(fmaxf(fmaxf(mx, x0), fmaxf(x1, x2)), x3);
            mn = fminf(fminf(fminf(mn, x0), fminf(x1, x2)), x3);
            tot += (x0 + x1) + (x2 + x3);
        } else {
            // -INF sentinel: never >= mid (finite or NaN) -> contributes
            // nothing to the Large cluster, exactly like absent samples.
            s[k * 4 + 0] = -INFINITY; s[k * 4 + 1] = -INFINITY;
            s[k * 4 + 2] = -INFINITY; s[k * 4 + 3] = -INFINITY;
        }
    }

    // wave butterfly: all lanes end with row max/min/total
    #pragma unroll
    for (int m = 1; m < 64; m <<= 1) {
        mx  = fmaxf(mx, __shfl_xor(mx, m));
        mn  = fminf(mn, __shfl_xor(mn, m));
        tot += __shfl_xor(tot, m);
    }

    // 2-means via midpoint threshold (mL>=mS invariant: |x-mL|<=|x-mS|
    // <=> x>=mid; tie->Large matches `<=`; NaN mid -> all-false matches the
    // reference's NaN-compare path). sumS = tot - sumL. (cnt,sumL) repeating
    // is a fixed point -> remaining iterations bit-identical; finalize with
    // exact divisions immediately.
    float mL = mx, mS = mn;
    float cntLast = 0.f;
    float prevSum = -1.f, prevCnt = -1.f;   // unreachable sentinels
    #pragma unroll 1
    for (int it = 0; it < KITER; ++it) {
        const float mid = 0.5f * (mL + mS);
        float sumL = 0.f;
        int   cw   = 0;
        #pragma unroll
        for (int j = 0; j < 32; ++j) {
            const float x  = s[j];
            const bool  bl = x >= mid;
            sumL += bl ? x : 0.f;
            cw   += (int)__popcll(__ballot(bl));   // wave-wide count, SALU
        }
        #pragma unroll
        for (int m = 1; m < 64; m <<= 1) sumL += __shfl_xor(sumL, m);

        const float cf = (float)cw;
        const float df = (float)DENSE - cf;
        const bool done = (it == KITER - 1) || (cf == prevCnt && sumL == prevSum);
        if (done) {
            mL = sumL / cf;                        // exact div for outputs
            mS = (tot - sumL) / df;
            // cnt==0: sumL=+0 -> 0/0=NaN matches ref. cnt==DENSE: force NaN
            // (tot-sumL may be +-eps -> +-inf otherwise).
            if (cw == DENSE) mS = __int_as_float(0x7fc00000);
            cntLast = cf;
            break;
        }
        mL = sumL * __builtin_amdgcn_rcpf(cf);     // fast rcp intermediates
        mS = (tot - sumL) * __builtin_amdgcn_rcpf(df);
        prevSum = sumL; prevCnt = cf;
    }

    if (lane == 0) {
        const bool contrast = ((mL - mS) > 0.005f) && (cntLast > 5.f);
        const float keep = contrast ? 1.f : 0.f;   // validRow already true
        // multiply (not select) so NaN cluster means propagate as in ref
        out[row * 2 + 0] = mL * keep;
        out[row * 2 + 1] = mS * keep;
    }
}

} // namespace

extern "C" void kernel_launch(void* const* d_in, const int* in_sizes, int n_in,
                              void* d_out, int out_size, void* d_ws, size_t ws_size,
                              hipStream_t stream) {
    const float* disp = (const float*)d_in[0];
    const float* fore = (const float*)d_in[1];
    const int*   cx   = (const int*)d_in[2];
    const int*   cy   = (const int*)d_in[3];
    const int*   bxp  = (const int*)d_in[4];
    const int*   byp  = (const int*)d_in[5];
    float* out  = (float*)d_out;
    int* flags  = (int*)d_ws;   // 5000 ints = 20 KB << ws_size; fully
                                // rewritten by phase A every call (ws is
                                // re-poisoned 0xAA before each launch)

    validity_kernel<<<(N + 255) / 256, 256, 0, stream>>>(disp, fore, cx, cy, flags, out);
    kmeans_kernel<<<N / RPB, 256, 0, stream>>>(disp, cx, cy, bxp, byp, flags, out);
}

// Round 9
// 122.728 us; speedup vs baseline: 1.0901x; 1.0901x over previous
//
#include <hip/hip_runtime.h>

namespace {

constexpr int Bn    = 10;
constexpr int H     = 320;
constexpr int W     = 1024;
constexpr int PTS   = 500;
constexpr int DENSE = 2000;
constexpr int N     = Bn * PTS;   // 5000 rows
constexpr int HWp   = H * W;
constexpr int KITER = 10;
constexpr int RPB   = 4;          // one row per wave, 4 waves per block

// disp window: rows cy-7..cy+7, cols cx-11..cx+12 (padded to 24)
constexpr int WY   = 15;
constexpr int WX   = 24;
constexpr int WSZ  = WY * WX;       // 360 words = 1440 B per wave
constexpr int WOFF = 7 * WX + 11;   // center offset inside the window

// 1250 blocks x 256 threads; each WAVE owns one row end-to-end. No barriers:
// per-wave LDS slice, same-wave DS ops are in-order (validated rounds 3/6,
// absmax 0.0). Invalid rows (~78%) exit after a butterfly-free validity probe.
// launch_bounds(256,6): all 1250 blocks co-resident (<=6 blocks/CU needed),
// so every row's latency chain overlaps instead of queueing behind a slot cap.
__global__ __launch_bounds__(256, 6)
void rsbsp_kernel(const float* __restrict__ disp,
                  const float* __restrict__ forepred,
                  const int*   __restrict__ centerx,
                  const int*   __restrict__ centery,
                  const int*   __restrict__ bx,
                  const int*   __restrict__ by,
                  float*       __restrict__ out)
{
    __shared__ float win[RPB][WSZ];

    const int wid  = threadIdx.x >> 6;
    const int lane = threadIdx.x & 63;
    const int row  = blockIdx.x * RPB + wid;   // 0..4999
    const int b    = row / PTS;
    const int cx   = centerx[row];
    const int cy   = centery[row];
    const float* db = disp     + b * HWp;
    const float* fb = forepred + b * HWp;

    // ---- validity, per-wave, butterfly-free.
    //      mgv>0.1  <=>  max(v*ind,3)-3 > 0.1  <=>  ind && (some tap > 3.1).
    //      Lanes 0..8 each compute one sobel-x tap of the 3x3 maxpool window
    //      (centers >=11 from borders: SAME padding / border-zeroing are
    //      unreachable); one __any() ballot makes the result wave-uniform.
    const float dcen = db[cy * W + cx];   // issue first; uniform -> 1 line
    float v = 0.f;
    if (lane < 9) {
        const int dy = lane / 3, dx = lane % 3;
        const float* fp = fb + (cy - 2 + dy) * W + (cx - 2 + dx);
        const float g = (fp[2]         - fp[0])
                + 2.f * (fp[W + 2]     - fp[W])
                +       (fp[2 * W + 2] - fp[2 * W]);
        v = fabsf(g);
    }
    const bool validRow = (dcen > 0.007f) && __any(v > 3.1f);  // wave-uniform

    if (!validRow) {
        // Reference: out = km * keep with keep=0; km is provably finite here
        // (Large cluster always retains the max sample), so exact zeros match.
        if (lane == 0) { out[row * 2 + 0] = 0.f; out[row * 2 + 1] = 0.f; }
        return;                            // wave-level exit, no barriers exist
    }

    // ---- valid path: stage the 15x24 disp window into this wave's LDS slice
    float* wl = win[wid];
    const int gbase = (cy - 7) * W + (cx - 11);
    #pragma unroll
    for (int i = 0; i < 6; ++i) {
        const int w = lane + 64 * i;
        if (w < WSZ) {
            const unsigned r = (unsigned)w / 24u;
            const unsigned c = (unsigned)w - r * 24u;
            wl[w] = db[gbase + r * W + c];
        }
    }

    // ---- gather 2000 samples (32/lane) from the LDS window; bx/by as int4.
    //      Same-wave ds_write -> ds_read: in-order per wave, no barrier needed.
    const int4* bx4 = reinterpret_cast<const int4*>(bx + row * DENSE);
    const int4* by4 = reinterpret_cast<const int4*>(by + row * DENSE);

    float s[32];
    float mx = -INFINITY, mn = INFINITY, tot = 0.f;
    #pragma unroll
    for (int k = 0; k < 8; ++k) {
        const int q = lane + 64 * k;        // int4 index, 500 total
        if (q < DENSE / 4) {                 // only k==7 partially masked
            const int4 xb = bx4[q];
            const int4 yb = by4[q];
            const float x0 = wl[yb.x * WX + xb.x + WOFF];
            const float x1 = wl[yb.y * WX + xb.y + WOFF];
            const float x2 = wl[yb.z * WX + xb.z + WOFF];
            const float x3 = wl[yb.w * WX + xb.w + WOFF];
            s[k * 4 + 0] = x0; s[k * 4 + 1] = x1;
            s[k * 4 + 2] = x2; s[k * 4 + 3] = x3;
            mx = fmaxf(fmaxf(fmaxf(mx, x0), fmaxf(x1, x2)), x3);
            mn = fminf(fminf(fminf(mn, x0), fminf(x1, x2)), x3);
            tot += (x0 + x1) + (x2 + x3);
        } else {
            // -INF sentinel: never >= mid (finite or NaN) -> contributes
            // nothing to the Large cluster, exactly like absent samples.
            s[k * 4 + 0] = -INFINITY; s[k * 4 + 1] = -INFINITY;
            s[k * 4 + 2] = -INFINITY; s[k * 4 + 3] = -INFINITY;
        }
    }

    // wave butterfly: all lanes end with row max/min/total
    #pragma unroll
    for (int m = 1; m < 64; m <<= 1) {
        mx  = fmaxf(mx, __shfl_xor(mx, m));
        mn  = fminf(mn, __shfl_xor(mn, m));
        tot += __shfl_xor(tot, m);
    }

    // ---- 2-means via midpoint threshold (mL>=mS invariant: |x-mL|<=|x-mS|
    //      <=> x>=mid; tie->Large matches `<=`; NaN mid -> all-false matches
    //      the reference's NaN-compare path). sumS = tot - sumL.
    //      (cnt,sumL) repeating is a fixed point -> remaining iterations are
    //      bit-identical; finalize immediately with exact divisions.
    float mL = mx, mS = mn;
    float cntLast = 0.f;
    float prevSum = -1.f, prevCnt = -1.f;   // unreachable sentinels
    #pragma unroll 1
    for (int it = 0; it < KITER; ++it) {
        const float mid = 0.5f * (mL + mS);
        float sumL = 0.f;
        int   cw   = 0;
        #pragma unroll
        for (int j = 0; j < 32; ++j) {
            const float x  = s[j];
            const bool  bl = x >= mid;
            sumL += bl ? x : 0.f;
            cw   += (int)__popcll(__ballot(bl));   // wave-wide count, SALU
        }
        #pragma unroll
        for (int m = 1; m < 64; m <<= 1) sumL += __shfl_xor(sumL, m);

        const float cf = (float)cw;
        const float df = (float)DENSE - cf;
        const bool done = (it == KITER - 1) || (cf == prevCnt && sumL == prevSum);
        if (done) {
            mL = sumL / cf;                        // exact div for outputs
            mS = (tot - sumL) / df;
            // cnt==0: sumL=+0 -> 0/0=NaN matches ref. cnt==DENSE: force NaN
            // (tot-sumL may be +-eps -> +-inf otherwise).
            if (cw == DENSE) mS = __int_as_float(0x7fc00000);
            cntLast = cf;
            break;
        }
        mL = sumL * __builtin_amdgcn_rcpf(cf);     // fast rcp for intermediates
        mS = (tot - sumL) * __builtin_amdgcn_rcpf(df);
        prevSum = sumL; prevCnt = cf;
    }

    if (lane == 0) {
        const bool contrast = ((mL - mS) > 0.005f) && (cntLast > 5.f);
        const float keep = contrast ? 1.f : 0.f;   // validRow already true
        // multiply (not select) so NaN cluster means propagate as in ref
        out[row * 2 + 0] = mL * keep;
        out[row * 2 + 1] = mS * keep;
    }
}

} // namespace

extern "C" void kernel_launch(void* const* d_in, const int* in_sizes, int n_in,
                              void* d_out, int out_size, void* d_ws, size_t ws_size,
                              hipStream_t stream) {
    const float* disp = (const float*)d_in[0];
    const float* fore = (const float*)d_in[1];
    const int*   cx   = (const int*)d_in[2];
    const int*   cy   = (const int*)d_in[3];
    const int*   bxp  = (const int*)d_in[4];
    const int*   byp  = (const int*)d_in[5];
    float* out = (float*)d_out;

    rsbsp_kernel<<<N / RPB, 256, 0, stream>>>(disp, fore, cx, cy, bxp, byp, out);
}